// Round 5
// baseline (111862.244 us; speedup 1.0000x reference)
//
#include <hip/hip_runtime.h>

// FFJORD density on MI355X (gfx950). B=65536 rows, DIM=128, HID=512, 32 RK4 steps x 4 evals.
// Round 5: SINGLE fused kernel. Rounds 2-4 all landed ~40ms regardless of GEMM structure
// -> dominant cost was ~5k small-grid launches + workspace-limited chunking. Now one WG
// (4 waves, 256 thr) owns 32 rows through ALL 128 dynamics evals:
//   S1: h1 = tanh(zs@W1z + t*w1t + b1)        A=ZS(LDS)   -> h1 into slot A
//   S2: h2 = tanh(h1@W2 + b2); g2 = g3*(1-h2^2)  A=slotA  -> h2 slot B, g2 slot A
//   S3: f  = h2@W3 + b3; accf/z/zs updates (regs)  A=slotB -> zs into slot B[0..8KB]
//   S4: g1 = (g2@W2T)*(1-h1^2)  (mask from regs)   A=slotA -> g1 slot A
//   S5: vJ = g1@W1zT; lp-acc -= wrk*rowsum(vJ*v)   A=slotA -> regs (v = +-1 sign mask)
// LDS = 2 x 32KB slots (64KB total, 2 WGs/CU). g3 = v@W3T once, kept packed in regs.
// Weights packed bf16 [k>>3][n][k&7] (B-frag layout) in ws (1.5MB total -> ws-size-proof).
// Launches: 6 packs + 1 fused. Grid 2048 WGs = 4 clean waves of 2/CU.

#define DIMV 128
#define HIDV 512

typedef float  floatx4 __attribute__((ext_vector_type(4)));
typedef short  short8  __attribute__((ext_vector_type(8)));

static __device__ __forceinline__ unsigned short f2bf(float x) {
    union { float f; unsigned int u; } c; c.f = x;
    unsigned int u = c.u;
    u += 0x7FFFu + ((u >> 16) & 1u);   // round-to-nearest-even
    return (unsigned short)(u >> 16);
}
static __device__ __forceinline__ float bf2f(unsigned short h) {
    union { unsigned int u; float f; } c; c.u = ((unsigned int)h) << 16;
    return c.f;
}
static __device__ __forceinline__ unsigned packbf(float a, float b) {
    return (unsigned)f2bf(a) | ((unsigned)f2bf(b) << 16);
}
static __device__ __forceinline__ float unpackbf(unsigned u, int hi) {
    return bf2f((unsigned short)(hi ? (u >> 16) : (u & 0xffff)));
}
static __device__ __forceinline__ float fast_tanh(float x) {
    x = fminf(8.0f, fmaxf(-8.0f, x));
    float e = exp2f(x * 2.8853900817779268f);            // exp(2x)
    return (e - 1.0f) * __builtin_amdgcn_rcpf(e + 1.0f); // (e-1)/(e+1)
}

// ---- weight packing: dst[(k>>3)*N*8 + n*8 + (k&7)] = bf16(W[k][n]) ------------
__global__ void pack_kernel(const float* __restrict__ src, unsigned short* __restrict__ dst,
                            int K, int N, int ld, int transpose) {
    int i = blockIdx.x * 256 + threadIdx.x;
    if (i >= K * N) return;
    int j  = i & 7;
    int n  = (i >> 3) % N;
    int k8 = (i >> 3) / N;
    int k  = k8 * 8 + j;
    float v = transpose ? src[n * ld + k] : src[k * ld + n];
    dst[i] = f2bf(v);
}

// C-layout (row=quad*4+r, col=colw+f*16+l16) -> frag-tile LDS offset (halves),
// for local 32-row buffer with KTrow k32-tiles per row; element r at +r*8.
static __device__ __forceinline__ int cbase(int m, int KTrow, int colw, int f,
                                            int quad, int l16) {
    return (((m * KTrow) + (colw >> 5) + (f >> 1)) << 9)
         + ((((quad << 2) + ((((f << 1) + (l16 >> 3)) & 3) << 4)) << 3) + (l16 & 7));
}

// K-loop: A-frags from LDS (2 m-tiles, tile (m*KT+kt)), B-frags from packed global.
template<int KT, int NF, int NDIM>
static __device__ __forceinline__ void mm_stage(const unsigned short* SAct,
        const unsigned short* __restrict__ Wp, int colw, int lane, int quad, int l16,
        floatx4 (&acc)[2][NF]) {
    #pragma unroll
    for (int m = 0; m < 2; ++m)
        #pragma unroll
        for (int f = 0; f < NF; ++f) {
            floatx4 zz = {0.f, 0.f, 0.f, 0.f};
            acc[m][f] = zz;
        }
    #pragma unroll
    for (int kt = 0; kt < KT; ++kt) {
        const int k8 = (kt << 2) + quad;
        short8 b[NF];
        #pragma unroll
        for (int f = 0; f < NF; ++f)
            b[f] = *reinterpret_cast<const short8*>(
                &Wp[((size_t)k8 * NDIM + colw + (f << 4) + l16) << 3]);
        short8 a[2];
        #pragma unroll
        for (int m = 0; m < 2; ++m)
            a[m] = *reinterpret_cast<const short8*>(&SAct[((m * KT + kt) << 9) + (lane << 3)]);
        #pragma unroll
        for (int m = 0; m < 2; ++m)
            #pragma unroll
            for (int f = 0; f < NF; ++f)
                acc[m][f] = __builtin_amdgcn_mfma_f32_16x16x32_bf16(a[m], b[f], acc[m][f], 0, 0, 0);
    }
}

struct FArgs {
    const float* x;
    const float* v;
    const float* W1;           // raw (for t-row 128)
    const float* b1;
    const float* b2;
    const float* b3;
    const unsigned short* W1zp;
    const unsigned short* W2p;
    const unsigned short* W3p;
    const unsigned short* W2Tp;
    const unsigned short* W1zTp;
    const unsigned short* W3Tp;
    float* out;
};

__global__ __launch_bounds__(256, 2) void ffjord_fused(FArgs p) {
    __shared__ __align__(16) unsigned short SA[16384];   // h1 -> g2 -> g1
    __shared__ __align__(16) unsigned short SB[16384];   // h2 ; zs in [0..4096)
    const int tid  = threadIdx.x;
    const int wave = tid >> 6, lane = tid & 63;
    const int quad = lane >> 4, l16 = lane & 15;
    const int row0 = blockIdx.x * 32;
    const int colw2 = wave * 128;   // N=512 stages
    const int colw3 = wave * 32;    // N=128 stages

    // ---- stage zs -> SB frags, v -> SA frags (once) ----
    #pragma unroll
    for (int i = 0; i < 16; ++i) {
        const int idx = tid * 16 + i;             // 8 tiles x 512 halves
        const int tile = idx >> 9, off = idx & 511;
        const int rc = off >> 3;
        const int row = (tile >> 2) * 16 + (rc & 15);
        const int col = (tile & 3) * 32 + (rc >> 4) * 8 + (off & 7);
        const size_t g = (size_t)(row0 + row) * 128 + col;
        SB[idx] = f2bf(p.x[g]);
        SA[idx] = f2bf(p.v[g]);
    }

    // ---- persistent per-lane state ----
    float z[2][2][4], accf[2][2][4];
    unsigned vsign = 0;
    float b1c[8], w1c[8], b2c[8], b3c[2], lpp[8];
    #pragma unroll
    for (int i = 0; i < 8; ++i) lpp[i] = 0.0f;
    #pragma unroll
    for (int f = 0; f < 8; ++f) {
        const int col = colw2 + (f << 4) + l16;
        b1c[f] = p.b1[col];
        w1c[f] = p.W1[128 * 512 + col];
        b2c[f] = p.b2[col];
    }
    #pragma unroll
    for (int f = 0; f < 2; ++f) b3c[f] = p.b3[colw3 + (f << 4) + l16];
    #pragma unroll
    for (int m = 0; m < 2; ++m)
        #pragma unroll
        for (int f = 0; f < 2; ++f)
            #pragma unroll
            for (int r = 0; r < 4; ++r) {
                const size_t g = (size_t)(row0 + m * 16 + quad * 4 + r) * 128
                               + colw3 + (f << 4) + l16;
                z[m][f][r] = p.x[g];
                accf[m][f][r] = 0.0f;
                if (p.v[g] < 0.0f) vsign |= 1u << (m * 8 + f * 4 + r);
            }
    __syncthreads();

    // ---- g3 = v @ W3^T (once), kept packed in regs at S2-epilogue positions ----
    unsigned g3p[2][8][2];
    {
        floatx4 acc[2][8];
        mm_stage<4, 8, 512>(SA, p.W3Tp, colw2, lane, quad, l16, acc);
        #pragma unroll
        for (int m = 0; m < 2; ++m)
            #pragma unroll
            for (int f = 0; f < 8; ++f) {
                g3p[m][f][0] = packbf(acc[m][f][0], acc[m][f][1]);
                g3p[m][f][1] = packbf(acc[m][f][2], acc[m][f][3]);
            }
    }
    unsigned m1p[2][8][2];   // (1 - h1^2) at S1/S4 C-positions

    const float dt = 0.03125f;
    #pragma unroll 1
    for (int e = 0; e < 128; ++e) {
        const int s = e & 3;
        const float t = (float)(e >> 2) * dt + ((s == 0) ? 0.f : ((s == 3) ? dt : 0.5f * dt));
        const float wrk = (s == 0 || s == 3) ? (dt / 6.0f) : (dt / 3.0f);
        const float cnext = (s < 2) ? (0.5f * dt) : ((s == 2) ? dt : 0.f);
        const bool s0 = (s == 0), s3 = (s == 3);

        __syncthreads();                                   // B0: SA free (prev S5 done)
        {   // ---- S1: h1 ----
            floatx4 acc[2][8];
            mm_stage<4, 8, 512>(SB, p.W1zp, colw2, lane, quad, l16, acc);
            #pragma unroll
            for (int m = 0; m < 2; ++m)
                #pragma unroll
                for (int f = 0; f < 8; ++f) {
                    const int base = cbase(m, 16, colw2, f, quad, l16);
                    float mv[4];
                    #pragma unroll
                    for (int r = 0; r < 4; ++r) {
                        const float h = fast_tanh(acc[m][f][r] + b1c[f] + t * w1c[f]);
                        SA[base + (r << 3)] = f2bf(h);
                        mv[r] = 1.0f - h * h;
                    }
                    m1p[m][f][0] = packbf(mv[0], mv[1]);
                    m1p[m][f][1] = packbf(mv[2], mv[3]);
                }
        }
        __syncthreads();                                   // B1: h1 ready
        {   // ---- S2: h2, g2 ----
            floatx4 acc[2][8];
            mm_stage<16, 8, 512>(SA, p.W2p, colw2, lane, quad, l16, acc);
            __syncthreads();                               // B2: all done reading h1
            #pragma unroll
            for (int m = 0; m < 2; ++m)
                #pragma unroll
                for (int f = 0; f < 8; ++f) {
                    const int base = cbase(m, 16, colw2, f, quad, l16);
                    #pragma unroll
                    for (int r = 0; r < 4; ++r) {
                        const float h = fast_tanh(acc[m][f][r] + b2c[f]);
                        SB[base + (r << 3)] = f2bf(h);
                        const float g3v = unpackbf(g3p[m][f][r >> 1], r & 1);
                        SA[base + (r << 3)] = f2bf(g3v * (1.0f - h * h));
                    }
                }
        }
        __syncthreads();                                   // B3a: h2/g2 ready
        {   // ---- S3: f, state updates, zs ----
            floatx4 acc[2][2];
            mm_stage<16, 2, 128>(SB, p.W3p, colw3, lane, quad, l16, acc);
            __syncthreads();                               // B3: all done reading h2
            #pragma unroll
            for (int m = 0; m < 2; ++m)
                #pragma unroll
                for (int f = 0; f < 2; ++f) {
                    const int base = cbase(m, 4, colw3, f, quad, l16);
                    #pragma unroll
                    for (int r = 0; r < 4; ++r) {
                        const float fv = acc[m][f][r] + b3c[f];
                        const float an = wrk * fv + (s0 ? 0.0f : accf[m][f][r]);
                        float zsv;
                        if (s3) { z[m][f][r] += an; zsv = z[m][f][r]; }
                        else    { accf[m][f][r] = an; zsv = z[m][f][r] + cnext * fv; }
                        SB[base + (r << 3)] = f2bf(zsv);
                    }
                }
        }
        {   // ---- S4: g1 ----
            floatx4 acc[2][8];
            mm_stage<16, 8, 512>(SA, p.W2Tp, colw2, lane, quad, l16, acc);
            __syncthreads();                               // B4: all done reading g2
            #pragma unroll
            for (int m = 0; m < 2; ++m)
                #pragma unroll
                for (int f = 0; f < 8; ++f) {
                    const int base = cbase(m, 16, colw2, f, quad, l16);
                    #pragma unroll
                    for (int r = 0; r < 4; ++r) {
                        const float m1v = unpackbf(m1p[m][f][r >> 1], r & 1);
                        SA[base + (r << 3)] = f2bf(acc[m][f][r] * m1v);
                    }
                }
        }
        __syncthreads();                                   // B5: g1 ready
        {   // ---- S5: vJ, divergence accumulation ----
            floatx4 acc[2][2];
            mm_stage<16, 2, 128>(SA, p.W1zTp, colw3, lane, quad, l16, acc);
            #pragma unroll
            for (int m = 0; m < 2; ++m)
                #pragma unroll
                for (int r = 0; r < 4; ++r) {
                    float ps = 0.0f;
                    #pragma unroll
                    for (int f = 0; f < 2; ++f) {
                        const float av = acc[m][f][r];
                        ps += ((vsign >> (m * 8 + f * 4 + r)) & 1) ? -av : av;
                    }
                    lpp[m * 4 + r] -= wrk * ps;
                }
        }
    }

    // ---- final: out = lp - 0.5*||z||^2 - 0.5*128*log(2pi) ----
    __syncthreads();
    float* SBf = (float*)SB;
    float z2[8];
    #pragma unroll
    for (int m = 0; m < 2; ++m)
        #pragma unroll
        for (int r = 0; r < 4; ++r)
            z2[m * 4 + r] = z[m][0][r] * z[m][0][r] + z[m][1][r] * z[m][1][r];
    #pragma unroll
    for (int i = 0; i < 8; ++i) {
        #pragma unroll
        for (int d = 1; d < 16; d <<= 1) {
            z2[i]  += __shfl_xor(z2[i], d);
            lpp[i] += __shfl_xor(lpp[i], d);
        }
    }
    if (l16 == 0) {
        #pragma unroll
        for (int m = 0; m < 2; ++m)
            #pragma unroll
            for (int r = 0; r < 4; ++r) {
                const int row = m * 16 + quad * 4 + r;
                SBf[row * 4 + wave]       = z2[m * 4 + r];
                SBf[128 + row * 4 + wave] = lpp[m * 4 + r];
            }
    }
    __syncthreads();
    if (tid < 32) {
        const float zt = SBf[tid * 4] + SBf[tid * 4 + 1] + SBf[tid * 4 + 2] + SBf[tid * 4 + 3];
        const float lt = SBf[128 + tid * 4] + SBf[128 + tid * 4 + 1]
                       + SBf[128 + tid * 4 + 2] + SBf[128 + tid * 4 + 3];
        p.out[row0 + tid] = lt - 0.5f * zt - 117.6241322501981f;
    }
}

extern "C" void kernel_launch(void* const* d_in, const int* in_sizes, int n_in,
                              void* d_out, int out_size, void* d_ws, size_t ws_size,
                              hipStream_t stream) {
    (void)n_in; (void)out_size;
    const float* x  = (const float*)d_in[0];
    const float* v  = (const float*)d_in[1];
    const float* W1 = (const float*)d_in[2];
    const float* b1 = (const float*)d_in[3];
    const float* W2 = (const float*)d_in[4];
    const float* b2 = (const float*)d_in[5];
    const float* W3 = (const float*)d_in[6];
    const float* b3 = (const float*)d_in[7];
    float* out = (float*)d_out;
    const int B = in_sizes[0] / DIMV;   // 65536

    auto al = [](size_t s) { return (s + 255) & ~(size_t)255; };
    if (ws_size < al(128*512*2) * 4 + al(512*512*2) * 2) return;  // ~1.5MB needed

    char* w = (char*)d_ws;
    auto alloc = [&](size_t bytes) { char* p = w; w += al(bytes); return p; };
    unsigned short* W1zp  = (unsigned short*)alloc(128 * 512 * 2);
    unsigned short* W3p   = (unsigned short*)alloc(512 * 128 * 2);
    unsigned short* W1zTp = (unsigned short*)alloc(512 * 128 * 2);
    unsigned short* W3Tp  = (unsigned short*)alloc(128 * 512 * 2);
    unsigned short* W2p   = (unsigned short*)alloc(512 * 512 * 2);
    unsigned short* W2Tp  = (unsigned short*)alloc(512 * 512 * 2);

    auto pack = [&](const float* src, unsigned short* dst, int K, int N, int ld, int tr) {
        pack_kernel<<<dim3((K * N + 255) / 256), dim3(256), 0, stream>>>(src, dst, K, N, ld, tr);
    };
    pack(W1, W1zp,  128, 512, 512, 0);
    pack(W2, W2p,   512, 512, 512, 0);
    pack(W3, W3p,   512, 128, 128, 0);
    pack(W2, W2Tp,  512, 512, 512, 1);
    pack(W1, W1zTp, 512, 128, 512, 1);
    pack(W3, W3Tp,  128, 512, 128, 1);

    FArgs p{};
    p.x = x; p.v = v; p.W1 = W1; p.b1 = b1; p.b2 = b2; p.b3 = b3;
    p.W1zp = W1zp; p.W2p = W2p; p.W3p = W3p;
    p.W2Tp = W2Tp; p.W1zTp = W1zTp; p.W3Tp = W3Tp;
    p.out = out;
    ffjord_fused<<<dim3(B / 32), dim3(256), 0, stream>>>(p);
}

// Round 7
// 88372.772 us; speedup vs baseline: 1.2658x; 1.2658x over previous
//
#include <hip/hip_runtime.h>

// FFJORD density on MI355X (gfx950). B=65536, DIM=128, HID=512, 32 RK4 steps x 4 evals.
// Round 7 = Round 6 resubmitted verbatim (R6 bench died on GPUAcquisitionTimeout —
// infra, not kernel). ONE kernel per dynamics eval (5 fused stages, barriers between),
// 128-row WGs. R5 lesson (counters): weight traffic = (B/rowsPerWG)*1.4MB*128; 32-row
// WGs -> 369GB demand, 112GB HBM-side at ~1.1TB/s = the whole 111ms. 128-row WGs (92GB)
// + same-stage homogeneity (R2 ran this at ~5TB/s effective) + per-eval fusion (131
// launches vs ~650, activations stay WG-local/L2-hot in frag layout via global_load_lds).
//   S1: h1 = tanh(zs @ W1z + t*w1t + b1)
//   S2: h2 = tanh(h1 @ W2 + b2); g2 = g3*(1-h2^2)
//   S3: f  = h2 @ W3 + b3; accf += wrk*f; zs = bf16(z + cnext*f)  (s3: z += accf)
//   S4: g1 = (g2 @ W2^T) * (1-h1^2)    [in place over h1; mask recomputed from h1]
//   S5: vJ = g1 @ W1z^T; accd += wrk*(-rowsum(vJ*v))              (s3: lp += accd)

#define DIMV 128
#define HIDV 512

typedef float  floatx4 __attribute__((ext_vector_type(4)));
typedef short  short8  __attribute__((ext_vector_type(8)));

static __device__ __forceinline__ unsigned short f2bf(float x) {
    union { float f; unsigned int u; } c; c.f = x;
    unsigned int u = c.u;
    u += 0x7FFFu + ((u >> 16) & 1u);
    return (unsigned short)(u >> 16);
}
static __device__ __forceinline__ float bf2f(unsigned short h) {
    union { unsigned int u; float f; } c; c.u = ((unsigned int)h) << 16;
    return c.f;
}
static __device__ __forceinline__ float fast_tanh(float x) {
    x = fminf(8.0f, fmaxf(-8.0f, x));
    float e = exp2f(x * 2.8853900817779268f);
    return (e - 1.0f) * __builtin_amdgcn_rcpf(e + 1.0f);
}
static __device__ __forceinline__ void gload_lds16(const void* g, void* l) {
    __builtin_amdgcn_global_load_lds(
        (const __attribute__((address_space(1))) unsigned int*)g,
        (__attribute__((address_space(3))) unsigned int*)l, 16, 0, 0);
}

// A-frag tile layout: tile = 16 rows x 32 k (512 halves); lane l holds elems l*8..l*8+7
// = A[m=l&15][k=(l>>4)*8+j]. Within-tile offset for C-epilogue element (quad,r,f,l16):
static __device__ __forceinline__ int finner(int f, int quad, int l16) {
    return ((((quad << 2) + ((((f << 1) + (l16 >> 3)) & 3) << 4)) << 3) + (l16 & 7));
}
// element offset for (row,col) in a [rows][KC] frag array (init path)
static __device__ __forceinline__ size_t fragoff(int row, int col, int KC) {
    return ((size_t)(row >> 4) * (KC >> 5) + (col >> 5)) * 512
         + (size_t)((((row & 15) + (((col >> 3) & 3) << 4)) << 3) + (col & 7));
}

__global__ void pack_kernel(const float* __restrict__ src, unsigned short* __restrict__ dst,
                            int K, int N, int ld, int transpose) {
    int i = blockIdx.x * 256 + threadIdx.x;
    if (i >= K * N) return;
    int j  = i & 7;
    int n  = (i >> 3) % N;
    int k8 = (i >> 3) / N;
    int k  = k8 * 8 + j;
    float v = transpose ? src[n * ld + k] : src[k * ld + n];
    dst[i] = f2bf(v);
}

__global__ void init_k(const float* __restrict__ x, float* __restrict__ z,
                       unsigned short* __restrict__ zs, float* __restrict__ lp,
                       int n, int nrows) {
    int i = blockIdx.x * 256 + threadIdx.x;
    if (i < n) {
        float val = x[i]; z[i] = val;
        zs[fragoff(i >> 7, i & 127, 128)] = f2bf(val);
    }
    if (i < nrows) lp[i] = 0.0f;
}

struct EArgs {
    unsigned short *zs, *h1, *h2, *g2;
    const unsigned short *g3;
    float *z, *accf, *lp, *accd;
    const float *v, *W1, *b1, *b2, *b3;
    const unsigned short *W1zp, *W2p, *W3p, *W2Tp, *W1zTp;
    float t, wrk, cnext;
    int s0, s3;
};

#define STAGE32(SRC, KTrow, kt0)                                                  \
    {   __syncthreads();                                                          \
        _Pragma("unroll")                                                         \
        for (int i = 0; i < 8; ++i) {                                             \
            const int tt = (i << 2) + wave;                                       \
            gload_lds16((SRC) + (((size_t)(rt0 + (tt >> 2)) * (KTrow)             \
                                  + (kt0) + (tt & 3)) << 9) + (lane << 3),        \
                        &As[tt << 9]);                                            \
        }                                                                         \
        __syncthreads();                                                          \
    }

__global__ __launch_bounds__(256, 2) void eval_k(EArgs p) {
    __shared__ __align__(16) unsigned short As[16384];   // 32 frag tiles = 128r x 128k
    const int tid  = threadIdx.x;
    const int wave = tid >> 6, lane = tid & 63;
    const int quad = lane >> 4, l16 = lane & 15;
    const int row0 = blockIdx.x * 128;
    const int rt0  = row0 >> 4;

    // ================= S1: h1 = tanh(zs @ W1z + t*w1t + b1) =================
    STAGE32(p.zs, 4, 0)
    #pragma unroll
    for (int cc = 0; cc < 2; ++cc) {
        floatx4 acc[8][4];
        #pragma unroll
        for (int m = 0; m < 8; ++m)
            #pragma unroll
            for (int f = 0; f < 4; ++f) { floatx4 zz = {0,0,0,0}; acc[m][f] = zz; }
        const int colwc = cc * 256 + wave * 64;
        #pragma unroll
        for (int kt = 0; kt < 4; ++kt) {
            const int k8 = (kt << 2) + quad;
            short8 b[4];
            #pragma unroll
            for (int f = 0; f < 4; ++f)
                b[f] = *reinterpret_cast<const short8*>(
                    &p.W1zp[((size_t)k8 * 512 + colwc + (f << 4) + l16) << 3]);
            #pragma unroll
            for (int m = 0; m < 8; ++m) {
                const short8 a = *reinterpret_cast<const short8*>(
                    &As[(((m << 2) + kt) << 9) + (lane << 3)]);
                #pragma unroll
                for (int f = 0; f < 4; ++f)
                    acc[m][f] = __builtin_amdgcn_mfma_f32_16x16x32_bf16(a, b[f], acc[m][f], 0, 0, 0);
            }
        }
        #pragma unroll
        for (int m = 0; m < 8; ++m)
            #pragma unroll
            for (int f = 0; f < 4; ++f) {
                const int col = colwc + (f << 4) + l16;
                const float bias = p.b1[col] + p.t * p.W1[128 * 512 + col];
                const size_t base = (((size_t)(rt0 + m) * 16) + (colwc >> 5) + (f >> 1)) * 512
                                  + finner(f, quad, l16);
                #pragma unroll
                for (int r = 0; r < 4; ++r)
                    p.h1[base + (r << 3)] = f2bf(fast_tanh(acc[m][f][r] + bias));
            }
    }

    // ============ S2: h2 = tanh(h1 @ W2 + b2); g2 = g3*(1-h2^2) ============
    #pragma unroll
    for (int cc = 0; cc < 2; ++cc) {
        floatx4 acc[8][4];
        #pragma unroll
        for (int m = 0; m < 8; ++m)
            #pragma unroll
            for (int f = 0; f < 4; ++f) { floatx4 zz = {0,0,0,0}; acc[m][f] = zz; }
        const int colwc = cc * 256 + wave * 64;
        for (int ph = 0; ph < 4; ++ph) {
            STAGE32(p.h1, 16, ph << 2)
            #pragma unroll
            for (int kt = 0; kt < 4; ++kt) {
                const int k8 = (((ph << 2) + kt) << 2) + quad;
                short8 b[4];
                #pragma unroll
                for (int f = 0; f < 4; ++f)
                    b[f] = *reinterpret_cast<const short8*>(
                        &p.W2p[((size_t)k8 * 512 + colwc + (f << 4) + l16) << 3]);
                #pragma unroll
                for (int m = 0; m < 8; ++m) {
                    const short8 a = *reinterpret_cast<const short8*>(
                        &As[(((m << 2) + kt) << 9) + (lane << 3)]);
                    #pragma unroll
                    for (int f = 0; f < 4; ++f)
                        acc[m][f] = __builtin_amdgcn_mfma_f32_16x16x32_bf16(a, b[f], acc[m][f], 0, 0, 0);
                }
            }
        }
        #pragma unroll
        for (int m = 0; m < 8; ++m)
            #pragma unroll
            for (int f = 0; f < 4; ++f) {
                const int col = colwc + (f << 4) + l16;
                const float bias = p.b2[col];
                const size_t base = (((size_t)(rt0 + m) * 16) + (colwc >> 5) + (f >> 1)) * 512
                                  + finner(f, quad, l16);
                #pragma unroll
                for (int r = 0; r < 4; ++r) {
                    const size_t o = base + (r << 3);
                    const float h = fast_tanh(acc[m][f][r] + bias);
                    p.h2[o] = f2bf(h);
                    p.g2[o] = f2bf(bf2f(p.g3[o]) * (1.0f - h * h));
                }
            }
    }

    // ===== S3: f = h2 @ W3 + b3; state updates (z, accf, zs; s3: z+=accf) =====
    {
        floatx4 acc[8][2];
        #pragma unroll
        for (int m = 0; m < 8; ++m)
            #pragma unroll
            for (int f = 0; f < 2; ++f) { floatx4 zz = {0,0,0,0}; acc[m][f] = zz; }
        for (int ph = 0; ph < 4; ++ph) {
            STAGE32(p.h2, 16, ph << 2)
            #pragma unroll
            for (int kt = 0; kt < 4; ++kt) {
                const int k8 = (((ph << 2) + kt) << 2) + quad;
                short8 b[2];
                #pragma unroll
                for (int f = 0; f < 2; ++f)
                    b[f] = *reinterpret_cast<const short8*>(
                        &p.W3p[((size_t)k8 * 128 + wave * 32 + (f << 4) + l16) << 3]);
                #pragma unroll
                for (int m = 0; m < 8; ++m) {
                    const short8 a = *reinterpret_cast<const short8*>(
                        &As[(((m << 2) + kt) << 9) + (lane << 3)]);
                    #pragma unroll
                    for (int f = 0; f < 2; ++f)
                        acc[m][f] = __builtin_amdgcn_mfma_f32_16x16x32_bf16(a, b[f], acc[m][f], 0, 0, 0);
                }
            }
        }
        #pragma unroll
        for (int m = 0; m < 8; ++m)
            #pragma unroll
            for (int f = 0; f < 2; ++f) {
                const int col = wave * 32 + (f << 4) + l16;
                const float bias = p.b3[col];
                const size_t zbase = (((size_t)(rt0 + m) * 4) + wave) * 512
                                   + finner(f, quad, l16);
                #pragma unroll
                for (int r = 0; r < 4; ++r) {
                    const int row = row0 + (m << 4) + (quad << 2) + r;
                    const size_t idxN = (size_t)row * 128 + col;
                    const float fv = acc[m][f][r] + bias;
                    const float a2 = p.wrk * fv + (p.s0 ? 0.0f : p.accf[idxN]);
                    float zsv;
                    if (p.s3) { const float zn = p.z[idxN] + a2; p.z[idxN] = zn; zsv = zn; }
                    else      { p.accf[idxN] = a2; zsv = p.z[idxN] + p.cnext * fv; }
                    p.zs[zbase + (r << 3)] = f2bf(zsv);
                }
            }
    }

    // ========== S4: g1 = (g2 @ W2^T) * (1-h1^2)  [in place over h1] ==========
    #pragma unroll
    for (int cc = 0; cc < 2; ++cc) {
        floatx4 acc[8][4];
        #pragma unroll
        for (int m = 0; m < 8; ++m)
            #pragma unroll
            for (int f = 0; f < 4; ++f) { floatx4 zz = {0,0,0,0}; acc[m][f] = zz; }
        const int colwc = cc * 256 + wave * 64;
        for (int ph = 0; ph < 4; ++ph) {
            STAGE32(p.g2, 16, ph << 2)
            #pragma unroll
            for (int kt = 0; kt < 4; ++kt) {
                const int k8 = (((ph << 2) + kt) << 2) + quad;
                short8 b[4];
                #pragma unroll
                for (int f = 0; f < 4; ++f)
                    b[f] = *reinterpret_cast<const short8*>(
                        &p.W2Tp[((size_t)k8 * 512 + colwc + (f << 4) + l16) << 3]);
                #pragma unroll
                for (int m = 0; m < 8; ++m) {
                    const short8 a = *reinterpret_cast<const short8*>(
                        &As[(((m << 2) + kt) << 9) + (lane << 3)]);
                    #pragma unroll
                    for (int f = 0; f < 4; ++f)
                        acc[m][f] = __builtin_amdgcn_mfma_f32_16x16x32_bf16(a, b[f], acc[m][f], 0, 0, 0);
                }
            }
        }
        #pragma unroll
        for (int m = 0; m < 8; ++m)
            #pragma unroll
            for (int f = 0; f < 4; ++f) {
                const size_t base = (((size_t)(rt0 + m) * 16) + (colwc >> 5) + (f >> 1)) * 512
                                  + finner(f, quad, l16);
                #pragma unroll
                for (int r = 0; r < 4; ++r) {
                    const size_t o = base + (r << 3);
                    const float h1v = bf2f(p.h1[o]);
                    p.h1[o] = f2bf(acc[m][f][r] * (1.0f - h1v * h1v));
                }
            }
    }
    __syncthreads();   // g1 (in h1) visible to all waves

    // ==== S5: vJ = g1 @ W1z^T; accd -= wrk*rowsum(vJ*v)  (M-split waves) ====
    {
        floatx4 acc[2][8];
        #pragma unroll
        for (int m = 0; m < 2; ++m)
            #pragma unroll
            for (int f = 0; f < 8; ++f) { floatx4 zz = {0,0,0,0}; acc[m][f] = zz; }
        const unsigned short* Ab = p.h1 + (lane << 3);
        for (int kt = 0; kt < 16; ++kt) {
            const int k8 = (kt << 2) + quad;
            short8 b[8];
            #pragma unroll
            for (int f = 0; f < 8; ++f)
                b[f] = *reinterpret_cast<const short8*>(
                    &p.W1zTp[((size_t)k8 * 128 + (f << 4) + l16) << 3]);
            short8 a[2];
            #pragma unroll
            for (int m = 0; m < 2; ++m)
                a[m] = *reinterpret_cast<const short8*>(
                    &Ab[((size_t)(rt0 + (wave << 1) + m) * 16 + kt) << 9]);
            #pragma unroll
            for (int m = 0; m < 2; ++m)
                #pragma unroll
                for (int f = 0; f < 8; ++f)
                    acc[m][f] = __builtin_amdgcn_mfma_f32_16x16x32_bf16(a[m], b[f], acc[m][f], 0, 0, 0);
        }
        #pragma unroll
        for (int m = 0; m < 2; ++m)
            #pragma unroll
            for (int r = 0; r < 4; ++r) {
                const int row = row0 + (wave << 5) + (m << 4) + (quad << 2) + r;
                float part = 0.0f;
                #pragma unroll
                for (int f = 0; f < 8; ++f)
                    part += acc[m][f][r] * p.v[(size_t)row * 128 + (f << 4) + l16];
                part += __shfl_xor(part, 1);
                part += __shfl_xor(part, 2);
                part += __shfl_xor(part, 4);
                part += __shfl_xor(part, 8);
                if (l16 == 0) {
                    const float a2 = p.wrk * (-part) + (p.s0 ? 0.0f : p.accd[row]);
                    if (p.s3) p.lp[row] += a2;
                    else      p.accd[row] = a2;
                }
            }
    }
}

// g3 = v @ W3^T (frag layout out), once per chunk
__global__ __launch_bounds__(256, 2) void g3_k(const float* __restrict__ v,
        const unsigned short* __restrict__ W3Tp, unsigned short* __restrict__ g3) {
    __shared__ __align__(16) unsigned short As[16384];
    const int tid  = threadIdx.x;
    const int wave = tid >> 6, lane = tid & 63;
    const int quad = lane >> 4, l16 = lane & 15;
    const int row0 = blockIdx.x * 128;
    const int rt0  = row0 >> 4;

    #pragma unroll
    for (int i = 0; i < 8; ++i) {
        const int t = (i << 2) + wave;
        const int row = row0 + ((t >> 2) << 4) + l16;
        const int colb = ((t & 3) << 5) + ((lane >> 4) << 3);
        float vals[8];
        *(float4*)&vals[0] = *(const float4*)&v[(size_t)row * 128 + colb];
        *(float4*)&vals[4] = *(const float4*)&v[(size_t)row * 128 + colb + 4];
        short8 sv;
        #pragma unroll
        for (int j = 0; j < 8; ++j) sv[j] = (short)f2bf(vals[j]);
        *reinterpret_cast<short8*>(&As[(t << 9) + (lane << 3)]) = sv;
    }
    __syncthreads();
    #pragma unroll
    for (int cc = 0; cc < 2; ++cc) {
        floatx4 acc[8][4];
        #pragma unroll
        for (int m = 0; m < 8; ++m)
            #pragma unroll
            for (int f = 0; f < 4; ++f) { floatx4 zz = {0,0,0,0}; acc[m][f] = zz; }
        const int colwc = cc * 256 + wave * 64;
        #pragma unroll
        for (int kt = 0; kt < 4; ++kt) {
            const int k8 = (kt << 2) + quad;
            short8 b[4];
            #pragma unroll
            for (int f = 0; f < 4; ++f)
                b[f] = *reinterpret_cast<const short8*>(
                    &W3Tp[((size_t)k8 * 512 + colwc + (f << 4) + l16) << 3]);
            #pragma unroll
            for (int m = 0; m < 8; ++m) {
                const short8 a = *reinterpret_cast<const short8*>(
                    &As[(((m << 2) + kt) << 9) + (lane << 3)]);
                #pragma unroll
                for (int f = 0; f < 4; ++f)
                    acc[m][f] = __builtin_amdgcn_mfma_f32_16x16x32_bf16(a, b[f], acc[m][f], 0, 0, 0);
            }
        }
        #pragma unroll
        for (int m = 0; m < 8; ++m)
            #pragma unroll
            for (int f = 0; f < 4; ++f) {
                const size_t base = (((size_t)(rt0 + m) * 16) + (colwc >> 5) + (f >> 1)) * 512
                                  + finner(f, quad, l16);
                #pragma unroll
                for (int r = 0; r < 4; ++r)
                    g3[base + (r << 3)] = f2bf(acc[m][f][r]);
            }
    }
}

__global__ void final_k(const float* __restrict__ z, const float* __restrict__ lp,
                        float* __restrict__ out) {
    const int tid = threadIdx.x;
    const int row = blockIdx.x * 16 + (tid >> 4);
    const int l16 = tid & 15;
    const float4* zr = (const float4*)&z[(size_t)row * 128 + (l16 << 3)];
    float4 a = zr[0], b = zr[1];
    float s = a.x*a.x + a.y*a.y + a.z*a.z + a.w*a.w
            + b.x*b.x + b.y*b.y + b.z*b.z + b.w*b.w;
    s += __shfl_xor(s, 1);
    s += __shfl_xor(s, 2);
    s += __shfl_xor(s, 4);
    s += __shfl_xor(s, 8);
    if (l16 == 0) out[row] = lp[row] - 0.5f * s - 117.6241322501981f;
}

extern "C" void kernel_launch(void* const* d_in, const int* in_sizes, int n_in,
                              void* d_out, int out_size, void* d_ws, size_t ws_size,
                              hipStream_t stream) {
    (void)n_in; (void)out_size;
    const float* x  = (const float*)d_in[0];
    const float* v  = (const float*)d_in[1];
    const float* W1 = (const float*)d_in[2];
    const float* b1 = (const float*)d_in[3];
    const float* W2 = (const float*)d_in[4];
    const float* b2 = (const float*)d_in[5];
    const float* W3 = (const float*)d_in[6];
    const float* b3 = (const float*)d_in[7];
    float* out = (float*)d_out;
    const int B = in_sizes[0] / DIMV;

    auto al = [](size_t s) { return (s + 255) & ~(size_t)255; };
    auto need_for = [&](size_t C) {
        return al(C * HIDV * 2) * 4               // h1, h2, g2, g3
             + al(C * DIMV * 2)                   // zs
             + al(C * DIMV * 4) * 2               // z, accf
             + al(C * 4) * 2                      // lp, accd
             + al(128 * 512 * 2) * 4 + al(512 * 512 * 2) * 2;
    };
    size_t C = (size_t)B;
    while (C > 1024 && need_for(C) > ws_size) C >>= 1;
    if (need_for(C) > ws_size) return;

    char* w = (char*)d_ws;
    auto alloc = [&](size_t bytes) { char* p = w; w += al(bytes); return p; };
    unsigned short* h1 = (unsigned short*)alloc(C * HIDV * 2);
    unsigned short* h2 = (unsigned short*)alloc(C * HIDV * 2);
    unsigned short* g2 = (unsigned short*)alloc(C * HIDV * 2);
    unsigned short* g3 = (unsigned short*)alloc(C * HIDV * 2);
    unsigned short* zs = (unsigned short*)alloc(C * DIMV * 2);
    float* z    = (float*)alloc(C * DIMV * 4);
    float* accf = (float*)alloc(C * DIMV * 4);
    float* lp   = (float*)alloc(C * 4);
    float* accd = (float*)alloc(C * 4);
    unsigned short* W1zp  = (unsigned short*)alloc(128 * 512 * 2);
    unsigned short* W3p   = (unsigned short*)alloc(512 * 128 * 2);
    unsigned short* W1zTp = (unsigned short*)alloc(512 * 128 * 2);
    unsigned short* W3Tp  = (unsigned short*)alloc(128 * 512 * 2);
    unsigned short* W2p   = (unsigned short*)alloc(512 * 512 * 2);
    unsigned short* W2Tp  = (unsigned short*)alloc(512 * 512 * 2);

    auto pack = [&](const float* src, unsigned short* dst, int K, int N, int ld, int tr) {
        pack_kernel<<<dim3((K * N + 255) / 256), dim3(256), 0, stream>>>(src, dst, K, N, ld, tr);
    };
    pack(W1, W1zp,  128, 512, 512, 0);
    pack(W2, W2p,   512, 512, 512, 0);
    pack(W3, W3p,   512, 128, 128, 0);
    pack(W2, W2Tp,  512, 512, 512, 1);
    pack(W1, W1zTp, 512, 128, 512, 1);
    pack(W3, W3Tp,  128, 512, 128, 1);

    const float dt = 1.0f / 32.0f;
    const float cs[4]  = {0.0f, 0.5f * dt, 0.5f * dt, dt};
    const float wr4[4] = {dt / 6.0f, dt / 3.0f, dt / 3.0f, dt / 6.0f};
    const int GM = (int)C / 128;

    for (int c0 = 0; c0 < B; c0 += (int)C) {
        const float* xc = x + (size_t)c0 * DIMV;
        const float* vc = v + (size_t)c0 * DIMV;

        init_k<<<dim3(((int)C * DIMV + 255) / 256), 256, 0, stream>>>(
            xc, z, zs, lp, (int)C * DIMV, (int)C);
        g3_k<<<dim3(GM), 256, 0, stream>>>(vc, W3Tp, g3);

        for (int e = 0; e < 128; ++e) {
            const int s = e & 3;
            EArgs p{};
            p.zs = zs; p.h1 = h1; p.h2 = h2; p.g2 = g2; p.g3 = g3;
            p.z = z; p.accf = accf; p.lp = lp; p.accd = accd;
            p.v = vc; p.W1 = W1; p.b1 = b1; p.b2 = b2; p.b3 = b3;
            p.W1zp = W1zp; p.W2p = W2p; p.W3p = W3p; p.W2Tp = W2Tp; p.W1zTp = W1zTp;
            p.t = (float)(e >> 2) * dt + cs[s];
            p.wrk = wr4[s];
            p.cnext = (s < 3) ? cs[s + 1] : 0.0f;
            p.s0 = (s == 0); p.s3 = (s == 3);
            eval_k<<<dim3(GM), 256, 0, stream>>>(p);
        }

        final_k<<<dim3((int)C / 16), 256, 0, stream>>>(z, lp, out + c0);
    }
}

// Round 8
// 51008.881 us; speedup vs baseline: 2.1930x; 1.7325x over previous
//
#include <hip/hip_runtime.h>

// FFJORD density on MI355X (gfx950). B=65536, DIM=128, HID=512, 32 RK4 steps x 4 evals.
// Round 8: refined per-stage structure (R2 = 38.6ms is the empirical best; fused variants
// R5/R7 lost to weight-L2 misses / >L3 activation sets). Changes vs R2:
//  1) chunk C capped at 32768 -> activation working set ~170MB < 256MB L3 (R7 lesson:
//     exceeding L3 = HBM round-trips = 2x loss).
//  2) frag-layout activations + global_load_lds staging (R7-verified machinery): no
//     VALU repack, 1 instr per 1KB tile.
//  3) 64-row WGs, 16KB LDS, __launch_bounds__(256,3): ~3 WGs/CU and 2x grid size for
//     latency hiding on the L3 path (R2 ran 2 WGs/CU with 18KB LDS + repack).
// Stages per eval (5 kernels):
//   S1: h1 = tanh(zs @ W1z + t*w1t + b1)
//   S2: h2 = tanh(h1 @ W2 + b2); g2 = g3*(1-h2^2)
//   S3: f  = h2 @ W3 + b3; accf += wrk*f; zs = bf16(z + cnext*f)  (s3: z += accf)
//   S4: g1 = (g2 @ W2^T) * (1-h1^2)   [in place over h1]
//   S5: vJ = g1 @ W1z^T; accd += wrk*(-rowsum(vJ*v))              (s3: lp += accd)

#define DIMV 128
#define HIDV 512

typedef float  floatx4 __attribute__((ext_vector_type(4)));
typedef short  short8  __attribute__((ext_vector_type(8)));

static __device__ __forceinline__ unsigned short f2bf(float x) {
    union { float f; unsigned int u; } c; c.f = x;
    unsigned int u = c.u;
    u += 0x7FFFu + ((u >> 16) & 1u);
    return (unsigned short)(u >> 16);
}
static __device__ __forceinline__ float bf2f(unsigned short h) {
    union { unsigned int u; float f; } c; c.u = ((unsigned int)h) << 16;
    return c.f;
}
static __device__ __forceinline__ float fast_tanh(float x) {
    x = fminf(8.0f, fmaxf(-8.0f, x));
    float e = exp2f(x * 2.8853900817779268f);
    return (e - 1.0f) * __builtin_amdgcn_rcpf(e + 1.0f);
}
static __device__ __forceinline__ void gload_lds16(const void* g, void* l) {
    __builtin_amdgcn_global_load_lds(
        (const __attribute__((address_space(1))) unsigned int*)g,
        (__attribute__((address_space(3))) unsigned int*)l, 16, 0, 0);
}

// A-frag tile: 16 rows x 32 k = 512 halves; lane l holds A[m=l&15][k=(l>>4)*8+j] at l*8+j.
static __device__ __forceinline__ int finner(int f, int quad, int l16) {
    return ((((quad << 2) + ((((f << 1) + (l16 >> 3)) & 3) << 4)) << 3) + (l16 & 7));
}
static __device__ __forceinline__ size_t fragoff(int row, int col, int KC) {
    return ((size_t)(row >> 4) * (KC >> 5) + (col >> 5)) * 512
         + (size_t)((((row & 15) + (((col >> 3) & 3) << 4)) << 3) + (col & 7));
}

__global__ void pack_kernel(const float* __restrict__ src, unsigned short* __restrict__ dst,
                            int K, int N, int ld, int transpose) {
    int i = blockIdx.x * 256 + threadIdx.x;
    if (i >= K * N) return;
    int j  = i & 7;
    int n  = (i >> 3) % N;
    int k8 = (i >> 3) / N;
    int k  = k8 * 8 + j;
    float v = transpose ? src[n * ld + k] : src[k * ld + n];
    dst[i] = f2bf(v);
}

__global__ void init_k(const float* __restrict__ x, float* __restrict__ z,
                       unsigned short* __restrict__ zs, float* __restrict__ lp,
                       int n, int nrows) {
    int i = blockIdx.x * 256 + threadIdx.x;
    if (i < n) {
        float val = x[i]; z[i] = val;
        zs[fragoff(i >> 7, i & 127, 128)] = f2bf(val);
    }
    if (i < nrows) lp[i] = 0.0f;
}

struct SArgs {
    unsigned short *zs, *h1, *h2, *g2;
    const unsigned short *g3;
    float *z, *accf, *lp, *accd;
    const float *v, *W1, *b1, *b2, *b3;
    const unsigned short *W1zp, *W2p, *W3p, *W2Tp, *W1zTp;
    float t, wrk, cnext;
    int s0, s3;
};

// Stage 16 frag tiles (64 rows x 128 k) into As via global_load_lds.
// SRC: frag array with KTrow k32-tiles per 16-row block; chunk starts at kt0.
#define STAGE64(SRC, KTrow, kt0)                                                  \
    {   __syncthreads();                                                          \
        _Pragma("unroll")                                                         \
        for (int i = 0; i < 4; ++i) {                                             \
            const int tt = (i << 2) + wave;                                       \
            gload_lds16((SRC) + (((size_t)(rt0 + (tt >> 2)) * (KTrow)             \
                                  + (kt0) + (tt & 3)) << 9) + (lane << 3),        \
                        &As[tt << 9]);                                            \
        }                                                                         \
        __syncthreads();                                                          \
    }

// ---- S1: h1 = tanh(zs @ W1z + t*w1t + b1).  64-row WG, K=128, N=512 (cc loop). ----
__global__ __launch_bounds__(256, 3) void s1_k(SArgs p) {
    __shared__ __align__(16) unsigned short As[8192];
    const int tid  = threadIdx.x;
    const int wave = tid >> 6, lane = tid & 63;
    const int quad = lane >> 4, l16 = lane & 15;
    const int rt0  = blockIdx.x << 2;

    STAGE64(p.zs, 4, 0)
    #pragma unroll
    for (int cc = 0; cc < 2; ++cc) {
        const int colwc = cc * 256 + wave * 64;
        floatx4 acc[4][4];
        #pragma unroll
        for (int m = 0; m < 4; ++m)
            #pragma unroll
            for (int f = 0; f < 4; ++f) { floatx4 zz = {0,0,0,0}; acc[m][f] = zz; }
        #pragma unroll
        for (int kt = 0; kt < 4; ++kt) {
            const int k8 = (kt << 2) + quad;
            short8 b[4];
            #pragma unroll
            for (int f = 0; f < 4; ++f)
                b[f] = *reinterpret_cast<const short8*>(
                    &p.W1zp[((size_t)k8 * 512 + colwc + (f << 4) + l16) << 3]);
            #pragma unroll
            for (int m = 0; m < 4; ++m) {
                const short8 a = *reinterpret_cast<const short8*>(
                    &As[(((m << 2) + kt) << 9) + (lane << 3)]);
                #pragma unroll
                for (int f = 0; f < 4; ++f)
                    acc[m][f] = __builtin_amdgcn_mfma_f32_16x16x32_bf16(a, b[f], acc[m][f], 0, 0, 0);
            }
        }
        #pragma unroll
        for (int m = 0; m < 4; ++m)
            #pragma unroll
            for (int f = 0; f < 4; ++f) {
                const int col = colwc + (f << 4) + l16;
                const float bias = p.b1[col] + p.t * p.W1[128 * 512 + col];
                const size_t base = ((size_t)(rt0 + m) * 16 + (colwc >> 5) + (f >> 1)) * 512
                                  + finner(f, quad, l16);
                #pragma unroll
                for (int r = 0; r < 4; ++r)
                    p.h1[base + (r << 3)] = f2bf(fast_tanh(acc[m][f][r] + bias));
            }
    }
}

// ---- S2: h2 = tanh(h1 @ W2 + b2); g2 = g3*(1-h2^2).  grid (GM,2), K=512. ----
__global__ __launch_bounds__(256, 3) void s2_k(SArgs p) {
    __shared__ __align__(16) unsigned short As[8192];
    const int tid  = threadIdx.x;
    const int wave = tid >> 6, lane = tid & 63;
    const int quad = lane >> 4, l16 = lane & 15;
    const int rt0  = blockIdx.x << 2;
    const int colwc = blockIdx.y * 256 + wave * 64;

    floatx4 acc[4][4];
    #pragma unroll
    for (int m = 0; m < 4; ++m)
        #pragma unroll
        for (int f = 0; f < 4; ++f) { floatx4 zz = {0,0,0,0}; acc[m][f] = zz; }
    for (int ph = 0; ph < 4; ++ph) {
        STAGE64(p.h1, 16, ph << 2)
        #pragma unroll
        for (int kt = 0; kt < 4; ++kt) {
            const int k8 = (((ph << 2) + kt) << 2) + quad;
            short8 b[4];
            #pragma unroll
            for (int f = 0; f < 4; ++f)
                b[f] = *reinterpret_cast<const short8*>(
                    &p.W2p[((size_t)k8 * 512 + colwc + (f << 4) + l16) << 3]);
            #pragma unroll
            for (int m = 0; m < 4; ++m) {
                const short8 a = *reinterpret_cast<const short8*>(
                    &As[(((m << 2) + kt) << 9) + (lane << 3)]);
                #pragma unroll
                for (int f = 0; f < 4; ++f)
                    acc[m][f] = __builtin_amdgcn_mfma_f32_16x16x32_bf16(a, b[f], acc[m][f], 0, 0, 0);
            }
        }
    }
    #pragma unroll
    for (int m = 0; m < 4; ++m)
        #pragma unroll
        for (int f = 0; f < 4; ++f) {
            const float bias = p.b2[colwc + (f << 4) + l16];
            const size_t base = ((size_t)(rt0 + m) * 16 + (colwc >> 5) + (f >> 1)) * 512
                              + finner(f, quad, l16);
            #pragma unroll
            for (int r = 0; r < 4; ++r) {
                const size_t o = base + (r << 3);
                const float h = fast_tanh(acc[m][f][r] + bias);
                p.h2[o] = f2bf(h);
                p.g2[o] = f2bf(bf2f(p.g3[o]) * (1.0f - h * h));
            }
        }
}

// ---- S3: f = h2 @ W3 + b3; state updates. K=512, N=128 (NF=2). ----
__global__ __launch_bounds__(256, 3) void s3_k(SArgs p) {
    __shared__ __align__(16) unsigned short As[8192];
    const int tid  = threadIdx.x;
    const int wave = tid >> 6, lane = tid & 63;
    const int quad = lane >> 4, l16 = lane & 15;
    const int rt0  = blockIdx.x << 2;

    floatx4 acc[4][2];
    #pragma unroll
    for (int m = 0; m < 4; ++m)
        #pragma unroll
        for (int f = 0; f < 2; ++f) { floatx4 zz = {0,0,0,0}; acc[m][f] = zz; }
    for (int ph = 0; ph < 4; ++ph) {
        STAGE64(p.h2, 16, ph << 2)
        #pragma unroll
        for (int kt = 0; kt < 4; ++kt) {
            const int k8 = (((ph << 2) + kt) << 2) + quad;
            short8 b[2];
            #pragma unroll
            for (int f = 0; f < 2; ++f)
                b[f] = *reinterpret_cast<const short8*>(
                    &p.W3p[((size_t)k8 * 128 + wave * 32 + (f << 4) + l16) << 3]);
            #pragma unroll
            for (int m = 0; m < 4; ++m) {
                const short8 a = *reinterpret_cast<const short8*>(
                    &As[(((m << 2) + kt) << 9) + (lane << 3)]);
                #pragma unroll
                for (int f = 0; f < 2; ++f)
                    acc[m][f] = __builtin_amdgcn_mfma_f32_16x16x32_bf16(a, b[f], acc[m][f], 0, 0, 0);
            }
        }
    }
    #pragma unroll
    for (int m = 0; m < 4; ++m)
        #pragma unroll
        for (int f = 0; f < 2; ++f) {
            const int col = wave * 32 + (f << 4) + l16;
            const float bias = p.b3[col];
            const size_t zbase = ((size_t)(rt0 + m) * 4 + wave) * 512 + finner(f, quad, l16);
            #pragma unroll
            for (int r = 0; r < 4; ++r) {
                const int row = (blockIdx.x << 6) + (m << 4) + (quad << 2) + r;
                const size_t idxN = (size_t)row * 128 + col;
                const float fv = acc[m][f][r] + bias;
                const float a2 = p.wrk * fv + (p.s0 ? 0.0f : p.accf[idxN]);
                float zsv;
                if (p.s3) { const float zn = p.z[idxN] + a2; p.z[idxN] = zn; zsv = zn; }
                else      { p.accf[idxN] = a2; zsv = p.z[idxN] + p.cnext * fv; }
                p.zs[zbase + (r << 3)] = f2bf(zsv);
            }
        }
}

// ---- S4: g1 = (g2 @ W2^T) * (1-h1^2), in place over h1. grid (GM,2). ----
__global__ __launch_bounds__(256, 3) void s4_k(SArgs p) {
    __shared__ __align__(16) unsigned short As[8192];
    const int tid  = threadIdx.x;
    const int wave = tid >> 6, lane = tid & 63;
    const int quad = lane >> 4, l16 = lane & 15;
    const int rt0  = blockIdx.x << 2;
    const int colwc = blockIdx.y * 256 + wave * 64;

    floatx4 acc[4][4];
    #pragma unroll
    for (int m = 0; m < 4; ++m)
        #pragma unroll
        for (int f = 0; f < 4; ++f) { floatx4 zz = {0,0,0,0}; acc[m][f] = zz; }
    for (int ph = 0; ph < 4; ++ph) {
        STAGE64(p.g2, 16, ph << 2)
        #pragma unroll
        for (int kt = 0; kt < 4; ++kt) {
            const int k8 = (((ph << 2) + kt) << 2) + quad;
            short8 b[4];
            #pragma unroll
            for (int f = 0; f < 4; ++f)
                b[f] = *reinterpret_cast<const short8*>(
                    &p.W2Tp[((size_t)k8 * 512 + colwc + (f << 4) + l16) << 3]);
            #pragma unroll
            for (int m = 0; m < 4; ++m) {
                const short8 a = *reinterpret_cast<const short8*>(
                    &As[(((m << 2) + kt) << 9) + (lane << 3)]);
                #pragma unroll
                for (int f = 0; f < 4; ++f)
                    acc[m][f] = __builtin_amdgcn_mfma_f32_16x16x32_bf16(a, b[f], acc[m][f], 0, 0, 0);
            }
        }
    }
    #pragma unroll
    for (int m = 0; m < 4; ++m)
        #pragma unroll
        for (int f = 0; f < 4; ++f) {
            const size_t base = ((size_t)(rt0 + m) * 16 + (colwc >> 5) + (f >> 1)) * 512
                              + finner(f, quad, l16);
            #pragma unroll
            for (int r = 0; r < 4; ++r) {
                const size_t o = base + (r << 3);
                const float h1v = bf2f(p.h1[o]);
                p.h1[o] = f2bf(acc[m][f][r] * (1.0f - h1v * h1v));
            }
        }
}

// ---- S5: vJ = g1 @ W1z^T; accd -= wrk*rowsum(vJ*v). M-split: wave owns 16 rows. ----
__global__ __launch_bounds__(256, 4) void s5_k(SArgs p) {
    const int tid  = threadIdx.x;
    const int wave = tid >> 6, lane = tid & 63;
    const int quad = lane >> 4, l16 = lane & 15;
    const int rt0  = blockIdx.x << 2;

    floatx4 acc[8];
    #pragma unroll
    for (int f = 0; f < 8; ++f) { floatx4 zz = {0,0,0,0}; acc[f] = zz; }
    const unsigned short* Ab = p.h1 + ((size_t)(rt0 + wave) << 13) + (lane << 3);
    for (int kt = 0; kt < 16; ++kt) {
        const int k8 = (kt << 2) + quad;
        short8 b[8];
        #pragma unroll
        for (int f = 0; f < 8; ++f)
            b[f] = *reinterpret_cast<const short8*>(
                &p.W1zTp[((size_t)k8 * 128 + (f << 4) + l16) << 3]);
        const short8 a = *reinterpret_cast<const short8*>(&Ab[(size_t)kt << 9]);
        #pragma unroll
        for (int f = 0; f < 8; ++f)
            acc[f] = __builtin_amdgcn_mfma_f32_16x16x32_bf16(a, b[f], acc[f], 0, 0, 0);
    }
    #pragma unroll
    for (int r = 0; r < 4; ++r) {
        const int row = (blockIdx.x << 6) + (wave << 4) + (quad << 2) + r;
        float part = 0.0f;
        #pragma unroll
        for (int f = 0; f < 8; ++f)
            part += acc[f][r] * p.v[(size_t)row * 128 + (f << 4) + l16];
        part += __shfl_xor(part, 1);
        part += __shfl_xor(part, 2);
        part += __shfl_xor(part, 4);
        part += __shfl_xor(part, 8);
        if (l16 == 0) {
            const float a2 = p.wrk * (-part) + (p.s0 ? 0.0f : p.accd[row]);
            if (p.s3) p.lp[row] += a2;
            else      p.accd[row] = a2;
        }
    }
}

// ---- g3 = v @ W3^T (frag layout), once per chunk. 64-row WG, VALU staging. ----
__global__ __launch_bounds__(256, 3) void g3_k(const float* __restrict__ v,
        const unsigned short* __restrict__ W3Tp, unsigned short* __restrict__ g3) {
    __shared__ __align__(16) unsigned short As[8192];
    const int tid  = threadIdx.x;
    const int wave = tid >> 6, lane = tid & 63;
    const int quad = lane >> 4, l16 = lane & 15;
    const int rt0  = blockIdx.x << 2;

    #pragma unroll
    for (int i = 0; i < 4; ++i) {
        const int t = (i << 2) + wave;
        const int row = (blockIdx.x << 6) + ((t >> 2) << 4) + l16;
        const int colb = ((t & 3) << 5) + ((lane >> 4) << 3);
        float vals[8];
        *(float4*)&vals[0] = *(const float4*)&v[(size_t)row * 128 + colb];
        *(float4*)&vals[4] = *(const float4*)&v[(size_t)row * 128 + colb + 4];
        short8 sv;
        #pragma unroll
        for (int j = 0; j < 8; ++j) sv[j] = (short)f2bf(vals[j]);
        *reinterpret_cast<short8*>(&As[(t << 9) + (lane << 3)]) = sv;
    }
    __syncthreads();
    #pragma unroll
    for (int cc = 0; cc < 2; ++cc) {
        const int colwc = cc * 256 + wave * 64;
        floatx4 acc[4][4];
        #pragma unroll
        for (int m = 0; m < 4; ++m)
            #pragma unroll
            for (int f = 0; f < 4; ++f) { floatx4 zz = {0,0,0,0}; acc[m][f] = zz; }
        #pragma unroll
        for (int kt = 0; kt < 4; ++kt) {
            const int k8 = (kt << 2) + quad;
            short8 b[4];
            #pragma unroll
            for (int f = 0; f < 4; ++f)
                b[f] = *reinterpret_cast<const short8*>(
                    &W3Tp[((size_t)k8 * 512 + colwc + (f << 4) + l16) << 3]);
            #pragma unroll
            for (int m = 0; m < 4; ++m) {
                const short8 a = *reinterpret_cast<const short8*>(
                    &As[(((m << 2) + kt) << 9) + (lane << 3)]);
                #pragma unroll
                for (int f = 0; f < 4; ++f)
                    acc[m][f] = __builtin_amdgcn_mfma_f32_16x16x32_bf16(a, b[f], acc[m][f], 0, 0, 0);
            }
        }
        #pragma unroll
        for (int m = 0; m < 4; ++m)
            #pragma unroll
            for (int f = 0; f < 4; ++f) {
                const size_t base = ((size_t)(rt0 + m) * 16 + (colwc >> 5) + (f >> 1)) * 512
                                  + finner(f, quad, l16);
                #pragma unroll
                for (int r = 0; r < 4; ++r)
                    g3[base + (r << 3)] = f2bf(acc[m][f][r]);
            }
    }
}

__global__ void final_k(const float* __restrict__ z, const float* __restrict__ lp,
                        float* __restrict__ out) {
    const int tid = threadIdx.x;
    const int row = blockIdx.x * 16 + (tid >> 4);
    const int l16 = tid & 15;
    const float4* zr = (const float4*)&z[(size_t)row * 128 + (l16 << 3)];
    float4 a = zr[0], b = zr[1];
    float s = a.x*a.x + a.y*a.y + a.z*a.z + a.w*a.w
            + b.x*b.x + b.y*b.y + b.z*b.z + b.w*b.w;
    s += __shfl_xor(s, 1);
    s += __shfl_xor(s, 2);
    s += __shfl_xor(s, 4);
    s += __shfl_xor(s, 8);
    if (l16 == 0) out[row] = lp[row] - 0.5f * s - 117.6241322501981f;
}

extern "C" void kernel_launch(void* const* d_in, const int* in_sizes, int n_in,
                              void* d_out, int out_size, void* d_ws, size_t ws_size,
                              hipStream_t stream) {
    (void)n_in; (void)out_size;
    const float* x  = (const float*)d_in[0];
    const float* v  = (const float*)d_in[1];
    const float* W1 = (const float*)d_in[2];
    const float* b1 = (const float*)d_in[3];
    const float* W2 = (const float*)d_in[4];
    const float* b2 = (const float*)d_in[5];
    const float* W3 = (const float*)d_in[6];
    const float* b3 = (const float*)d_in[7];
    float* out = (float*)d_out;
    const int B = in_sizes[0] / DIMV;

    auto al = [](size_t s) { return (s + 255) & ~(size_t)255; };
    auto need_for = [&](size_t C) {
        return al(C * HIDV * 2) * 4               // h1, h2, g2, g3
             + al(C * DIMV * 2)                   // zs
             + al(C * DIMV * 4) * 2               // z, accf
             + al(C * 4) * 2                      // lp, accd
             + al(128 * 512 * 2) * 4 + al(512 * 512 * 2) * 2;
    };
    size_t C = 32768;   // hard cap: activation set ~170MB must stay inside 256MB L3
    while (C > 1024 && need_for(C) > ws_size) C >>= 1;
    if (need_for(C) > ws_size) return;

    char* w = (char*)d_ws;
    auto alloc = [&](size_t bytes) { char* p = w; w += al(bytes); return p; };
    unsigned short* h1 = (unsigned short*)alloc(C * HIDV * 2);
    unsigned short* h2 = (unsigned short*)alloc(C * HIDV * 2);
    unsigned short* g2 = (unsigned short*)alloc(C * HIDV * 2);
    unsigned short* g3 = (unsigned short*)alloc(C * HIDV * 2);
    unsigned short* zs = (unsigned short*)alloc(C * DIMV * 2);
    float* z    = (float*)alloc(C * DIMV * 4);
    float* accf = (float*)alloc(C * DIMV * 4);
    float* lp   = (float*)alloc(C * 4);
    float* accd = (float*)alloc(C * 4);
    unsigned short* W1zp  = (unsigned short*)alloc(128 * 512 * 2);
    unsigned short* W3p   = (unsigned short*)alloc(512 * 128 * 2);
    unsigned short* W1zTp = (unsigned short*)alloc(512 * 128 * 2);
    unsigned short* W3Tp  = (unsigned short*)alloc(128 * 512 * 2);
    unsigned short* W2p   = (unsigned short*)alloc(512 * 512 * 2);
    unsigned short* W2Tp  = (unsigned short*)alloc(512 * 512 * 2);

    auto pack = [&](const float* src, unsigned short* dst, int K, int N, int ld, int tr) {
        pack_kernel<<<dim3((K * N + 255) / 256), dim3(256), 0, stream>>>(src, dst, K, N, ld, tr);
    };
    pack(W1, W1zp,  128, 512, 512, 0);
    pack(W2, W2p,   512, 512, 512, 0);
    pack(W3, W3p,   512, 128, 128, 0);
    pack(W2, W2Tp,  512, 512, 512, 1);
    pack(W1, W1zTp, 512, 128, 512, 1);
    pack(W3, W3Tp,  128, 512, 128, 1);

    const float dt = 1.0f / 32.0f;
    const float cs[4]  = {0.0f, 0.5f * dt, 0.5f * dt, dt};
    const float wr4[4] = {dt / 6.0f, dt / 3.0f, dt / 3.0f, dt / 6.0f};
    const int GM = (int)C / 64;

    for (int c0 = 0; c0 < B; c0 += (int)C) {
        const float* xc = x + (size_t)c0 * DIMV;
        const float* vc = v + (size_t)c0 * DIMV;

        init_k<<<dim3(((int)C * DIMV + 255) / 256), 256, 0, stream>>>(
            xc, z, zs, lp, (int)C * DIMV, (int)C);
        g3_k<<<dim3(GM), 256, 0, stream>>>(vc, W3Tp, g3);

        for (int e = 0; e < 128; ++e) {
            const int s = e & 3;
            SArgs p{};
            p.zs = zs; p.h1 = h1; p.h2 = h2; p.g2 = g2; p.g3 = g3;
            p.z = z; p.accf = accf; p.lp = lp; p.accd = accd;
            p.v = vc; p.W1 = W1; p.b1 = b1; p.b2 = b2; p.b3 = b3;
            p.W1zp = W1zp; p.W2p = W2p; p.W3p = W3p; p.W2Tp = W2Tp; p.W1zTp = W1zTp;
            p.t = (float)(e >> 2) * dt + cs[s];
            p.wrk = wr4[s];
            p.cnext = (s < 3) ? cs[s + 1] : 0.0f;
            p.s0 = (s == 0); p.s3 = (s == 3);
            s1_k<<<dim3(GM),    256, 0, stream>>>(p);
            s2_k<<<dim3(GM, 2), 256, 0, stream>>>(p);
            s3_k<<<dim3(GM),    256, 0, stream>>>(p);
            s4_k<<<dim3(GM, 2), 256, 0, stream>>>(p);
            s5_k<<<dim3(GM),    256, 0, stream>>>(p);
        }

        final_k<<<dim3((int)C / 16), 256, 0, stream>>>(z, lp, out + c0);
    }
}